// Round 1
// 895.096 us; speedup vs baseline: 1.0020x; 1.0020x over previous
//
#include <hip/hip_runtime.h>
#include <stdint.h>

#define E_  64
#define T_  128
#define D_  1024
#define H_  1024
#define N1_ 2048   // 2*HID

typedef __attribute__((ext_vector_type(8))) short bf16x8;
typedef __attribute__((ext_vector_type(4))) float f32x4;

// pack two f32 -> two bf16 (round-to-nearest-ish) in one v_perm
__device__ inline uint32_t pack_bf16(float lo, float hi) {
  union { float f; uint32_t u; } a, b;
  a.f = lo; b.f = hi;
  return __builtin_amdgcn_perm(b.u + 0x8000u, a.u + 0x8000u, 0x07060302u);
}
__device__ inline uint16_t f2bf(float f) {
  union { float f; uint32_t u; } v; v.f = f;
  return (uint16_t)((v.u + 0x8000u) >> 16);
}

#define SA 40  // LDS row stride in bf16: 80B -> every ds_read_b128 16B-aligned, ~2-way banks

// ---------------- Kernel 1: H = X @ W1 + b1 ; Act = swiglu(H) (bf16) ----------------
__global__ __launch_bounds__(256) void k1_gemm_swiglu(
    const float* __restrict__ X, const float* __restrict__ W1,
    const float* __restrict__ B1, uint16_t* __restrict__ Act) {
  int blk = blockIdx.x;                 // 1024 blocks
  int e  = (blk & 7) + ((blk >> 7) << 3);   // same-expert blocks share blk%8 (XCD)
  int nt = (blk >> 3) & 15;                 // 16 column tiles of 128 over N1=2048

  __shared__ uint16_t Asm[128 * SA];
  __shared__ uint16_t Bsm[128 * SA];

  int tid  = threadIdx.x;
  int lane = tid & 63;
  int w    = tid >> 6;
  int wm   = (w & 1) << 6;
  int wn   = (w >> 1) << 6;

  f32x4 acc[4][4];
  #pragma unroll
  for (int i = 0; i < 4; ++i)
    #pragma unroll
    for (int j = 0; j < 4; ++j) { f32x4 z = {0.f,0.f,0.f,0.f}; acc[i][j] = z; }

  const float* Xe  = X  + (size_t)e * T_ * D_;
  const float* W1e = W1 + (size_t)e * D_ * N1_ + nt * 128;

  // staging maps
  int a_k4 = tid & 7;    // A: float4 at k0=4*a_k4, rows a_m+32p
  int a_m  = tid >> 3;
  int b_n  = tid & 127;  // B: 4 k-rows per pass at column b_n (transpose on store)
  int b_kg = tid >> 7;

  float4 aR[4];
  float  bRa[4][4], bRb[4][4];   // 2-deep weight prefetch (named buffers: static indexing)

  auto loadA = [&](int kb) {
    #pragma unroll
    for (int p = 0; p < 4; ++p)
      aR[p] = *(const float4*)(Xe + (size_t)(a_m + 32 * p) * D_ + kb + 4 * a_k4);
  };
  auto loadB = [&](int kb, float (&bR)[4][4]) {
    #pragma unroll
    for (int p = 0; p < 4; ++p) {
      const float* src = W1e + (size_t)(kb + 4 * b_kg + 8 * p) * N1_ + b_n;
      bR[p][0] = src[0];
      bR[p][1] = src[N1_];
      bR[p][2] = src[2 * N1_];
      bR[p][3] = src[3 * N1_];
    }
  };
  auto storeA = [&]() {
    #pragma unroll
    for (int p = 0; p < 4; ++p) {
      int m = a_m + 32 * p;
      *(uint2*)&Asm[m * SA + 4 * a_k4] =
          make_uint2(pack_bf16(aR[p].x, aR[p].y), pack_bf16(aR[p].z, aR[p].w));
    }
  };
  auto storeB = [&](float (&bR)[4][4]) {
    #pragma unroll
    for (int p = 0; p < 4; ++p) {
      int r = 4 * b_kg + 8 * p;
      *(uint2*)&Bsm[b_n * SA + r] =
          make_uint2(pack_bf16(bR[p][0], bR[p][1]), pack_bf16(bR[p][2], bR[p][3]));
    }
  };
  auto compute = [&]() {
    bf16x8 af[4], bf[4];
    #pragma unroll
    for (int i = 0; i < 4; ++i) {
      af[i] = *(const bf16x8*)&Asm[(wm + i * 16 + (lane & 15)) * SA + ((lane >> 4) << 3)];
      bf[i] = *(const bf16x8*)&Bsm[(wn + i * 16 + (lane & 15)) * SA + ((lane >> 4) << 3)];
    }
    #pragma unroll
    for (int i = 0; i < 4; ++i)
      #pragma unroll
      for (int j = 0; j < 4; ++j)
        acc[i][j] = __builtin_amdgcn_mfma_f32_16x16x32_bf16(af[i], bf[j], acc[i][j], 0, 0, 0);
  };

  loadA(0);
  loadB(0, bRa);        // tile 0
  loadB(32, bRb);       // tile 1 — weights now 2 K-tiles in flight
  #pragma unroll 1
  for (int kt = 0; kt < D_ / 32; kt += 2) {
    // ---- even step: consume tile kt (bRa) ----
    __syncthreads();
    storeA(); storeB(bRa);
    if (kt + 2 < D_ / 32) loadB((kt + 2) * 32, bRa);   // refill 2 ahead
    loadA((kt + 1) * 32);                               // A stays 1-deep (L2-resident)
    __syncthreads();
    compute();

    // ---- odd step: consume tile kt+1 (bRb) ----
    __syncthreads();
    storeA(); storeB(bRb);
    if (kt + 3 < D_ / 32) loadB((kt + 3) * 32, bRb);
    if (kt + 2 < D_ / 32) loadA((kt + 2) * 32);
    __syncthreads();
    compute();
  }

  // epilogue: bias -> swiglu(pair via shfl_xor 1) -> Act bf16
  uint16_t* Acte = Act + (size_t)e * T_ * H_;
  #pragma unroll
  for (int j = 0; j < 4; ++j) {
    int col = nt * 128 + wn + j * 16 + (lane & 15);
    float bias = B1[e * N1_ + col];
    #pragma unroll
    for (int i = 0; i < 4; ++i) {
      #pragma unroll
      for (int r = 0; r < 4; ++r) {
        float h = acc[i][j][r] + bias;            // each lane adds ITS column's bias
        float partner = __shfl_xor(h, 1, 64);     // odd lane's (lin) value -> even lane
        if ((lane & 1) == 0) {
          float xg = fminf(h, 7.0f);
          float xl = fminf(fmaxf(partner, -7.0f), 7.0f);
          float sw = xg / (1.0f + __expf(-1.702f * xg));
          int m = wm + i * 16 + ((lane >> 4) << 2) + r;
          Acte[m * H_ + (col >> 1)] = f2bf(sw * (xl + 1.0f));
        }
      }
    }
  }
}

// ---------------- Kernel 2: OUT = Act @ W2 + b2 (fp32 out) ----------------
__global__ __launch_bounds__(256) void k2_gemm(
    const uint16_t* __restrict__ Act, const float* __restrict__ W2,
    const float* __restrict__ B2, float* __restrict__ OUT) {
  int blk = blockIdx.x;                 // 512 blocks
  int e  = (blk & 7) + ((blk >> 6) << 3);
  int nt = (blk >> 3) & 7;              // 8 column tiles of 128 over D=1024

  __shared__ uint16_t Asm[128 * SA];
  __shared__ uint16_t Bsm[128 * SA];

  int tid  = threadIdx.x;
  int lane = tid & 63;
  int w    = tid >> 6;
  int wm   = (w & 1) << 6;
  int wn   = (w >> 1) << 6;

  f32x4 acc[4][4];
  #pragma unroll
  for (int i = 0; i < 4; ++i)
    #pragma unroll
    for (int j = 0; j < 4; ++j) { f32x4 z = {0.f,0.f,0.f,0.f}; acc[i][j] = z; }

  const uint16_t* Ae  = Act + (size_t)e * T_ * H_;
  const float*    W2e = W2  + (size_t)e * H_ * D_ + nt * 128;

  int a_k2 = tid & 3;    // A: ushort8 (16B) at k0=8*a_k2, rows a_m+64p
  int a_m  = tid >> 2;
  int b_n  = tid & 127;
  int b_kg = tid >> 7;

  uint4 aR[2];
  float bRa[4][4], bRb[4][4];   // 2-deep weight prefetch

  auto loadA = [&](int kb) {
    #pragma unroll
    for (int p = 0; p < 2; ++p)
      aR[p] = *(const uint4*)(Ae + (size_t)(a_m + 64 * p) * H_ + kb + 8 * a_k2);
  };
  auto loadB = [&](int kb, float (&bR)[4][4]) {
    #pragma unroll
    for (int p = 0; p < 4; ++p) {
      const float* src = W2e + (size_t)(kb + 4 * b_kg + 8 * p) * D_ + b_n;
      bR[p][0] = src[0];
      bR[p][1] = src[D_];
      bR[p][2] = src[2 * D_];
      bR[p][3] = src[3 * D_];
    }
  };
  auto storeA = [&]() {
    #pragma unroll
    for (int p = 0; p < 2; ++p)
      *(uint4*)&Asm[(a_m + 64 * p) * SA + 8 * a_k2] = aR[p];
  };
  auto storeB = [&](float (&bR)[4][4]) {
    #pragma unroll
    for (int p = 0; p < 4; ++p) {
      int r = 4 * b_kg + 8 * p;
      *(uint2*)&Bsm[b_n * SA + r] =
          make_uint2(pack_bf16(bR[p][0], bR[p][1]), pack_bf16(bR[p][2], bR[p][3]));
    }
  };
  auto compute = [&]() {
    bf16x8 af[4], bf[4];
    #pragma unroll
    for (int i = 0; i < 4; ++i) {
      af[i] = *(const bf16x8*)&Asm[(wm + i * 16 + (lane & 15)) * SA + ((lane >> 4) << 3)];
      bf[i] = *(const bf16x8*)&Bsm[(wn + i * 16 + (lane & 15)) * SA + ((lane >> 4) << 3)];
    }
    #pragma unroll
    for (int i = 0; i < 4; ++i)
      #pragma unroll
      for (int j = 0; j < 4; ++j)
        acc[i][j] = __builtin_amdgcn_mfma_f32_16x16x32_bf16(af[i], bf[j], acc[i][j], 0, 0, 0);
  };

  loadA(0);
  loadB(0, bRa);
  loadB(32, bRb);
  #pragma unroll 1
  for (int kt = 0; kt < H_ / 32; kt += 2) {
    // ---- even step ----
    __syncthreads();
    storeA(); storeB(bRa);
    if (kt + 2 < H_ / 32) loadB((kt + 2) * 32, bRa);
    loadA((kt + 1) * 32);
    __syncthreads();
    compute();

    // ---- odd step ----
    __syncthreads();
    storeA(); storeB(bRb);
    if (kt + 3 < H_ / 32) loadB((kt + 3) * 32, bRb);
    if (kt + 2 < H_ / 32) loadA((kt + 2) * 32);
    __syncthreads();
    compute();
  }

  float* Oe = OUT + (size_t)e * T_ * D_;
  #pragma unroll
  for (int j = 0; j < 4; ++j) {
    int col = nt * 128 + wn + j * 16 + (lane & 15);
    float bias = B2[e * D_ + col];
    #pragma unroll
    for (int i = 0; i < 4; ++i) {
      #pragma unroll
      for (int r = 0; r < 4; ++r) {
        int m = wm + i * 16 + ((lane >> 4) << 2) + r;
        Oe[(size_t)m * D_ + col] = acc[i][j][r] + bias;
      }
    }
  }
}

extern "C" void kernel_launch(void* const* d_in, const int* in_sizes, int n_in,
                              void* d_out, int out_size, void* d_ws, size_t ws_size,
                              hipStream_t stream) {
  const float* X  = (const float*)d_in[0];
  const float* W1 = (const float*)d_in[1];
  const float* B1 = (const float*)d_in[2];
  const float* W2 = (const float*)d_in[3];
  const float* B2 = (const float*)d_in[4];
  float* OUT = (float*)d_out;
  uint16_t* Act = (uint16_t*)d_ws;  // 64*128*1024 bf16 = 16 MB

  k1_gemm_swiglu<<<dim3(E_ * 16), dim3(256), 0, stream>>>(X, W1, B1, Act);
  k2_gemm<<<dim3(E_ * 8), dim3(256), 0, stream>>>(Act, W2, B2, OUT);
}

// Round 2
// 887.368 us; speedup vs baseline: 1.0107x; 1.0087x over previous
//
#include <hip/hip_runtime.h>
#include <stdint.h>

#define E_  64
#define T_  128
#define D_  1024
#define H_  1024
#define N1_ 2048   // 2*HID

typedef __attribute__((ext_vector_type(8))) short bf16x8;
typedef __attribute__((ext_vector_type(4))) float f32x4;

// pack two f32 -> two bf16 (round-to-nearest-ish) in one v_perm
__device__ inline uint32_t pack_bf16(float lo, float hi) {
  union { float f; uint32_t u; } a, b;
  a.f = lo; b.f = hi;
  return __builtin_amdgcn_perm(b.u + 0x8000u, a.u + 0x8000u, 0x07060302u);
}
__device__ inline uint16_t f2bf(float f) {
  union { float f; uint32_t u; } v; v.f = f;
  return (uint16_t)((v.u + 0x8000u) >> 16);
}

#define SA 40  // LDS row stride in bf16: 80B -> every ds_read_b128 16B-aligned, ~2-way banks

// Raw-barrier pair: NO vmcnt drain (global loads stay in flight across barriers).
// b1: guards LDS overwrite (all waves finished ds_reads of previous tile).
// b2: guards LDS read (ds_writes visible: lgkmcnt(0) only).
#define BARRIER_PRE()                          \
  __builtin_amdgcn_s_barrier();                \
  __builtin_amdgcn_sched_barrier(0)
#define BARRIER_POST()                         \
  __builtin_amdgcn_sched_barrier(0);           \
  asm volatile("s_waitcnt lgkmcnt(0)");        \
  __builtin_amdgcn_s_barrier();                \
  __builtin_amdgcn_sched_barrier(0)

// ---------------- Kernel 1: H = X @ W1 + b1 ; Act = swiglu(H) (bf16) ----------------
__global__ __launch_bounds__(256) void k1_gemm_swiglu(
    const float* __restrict__ X, const float* __restrict__ W1,
    const float* __restrict__ B1, uint16_t* __restrict__ Act) {
  int blk = blockIdx.x;                 // 1024 blocks
  int e  = (blk & 7) + ((blk >> 7) << 3);   // same-expert blocks share blk%8 (XCD)
  int nt = (blk >> 3) & 15;                 // 16 column tiles of 128 over N1=2048

  __shared__ uint16_t Asm[128 * SA];
  __shared__ uint16_t Bsm[128 * SA];

  int tid  = threadIdx.x;
  int lane = tid & 63;
  int w    = tid >> 6;
  int wm   = (w & 1) << 6;
  int wn   = (w >> 1) << 6;

  f32x4 acc[4][4];
  #pragma unroll
  for (int i = 0; i < 4; ++i)
    #pragma unroll
    for (int j = 0; j < 4; ++j) { f32x4 z = {0.f,0.f,0.f,0.f}; acc[i][j] = z; }

  const float* Xe  = X  + (size_t)e * T_ * D_;
  const float* W1e = W1 + (size_t)e * D_ * N1_ + nt * 128;

  // staging maps
  int a_k4 = tid & 7;    // A: float4 at k0=4*a_k4, rows a_m+32p
  int a_m  = tid >> 3;
  int b_n  = tid & 127;  // B: 4 k-rows per pass at column b_n (transpose on store)
  int b_kg = tid >> 7;

  float4 aR[4];
  float  bRa[4][4], bRb[4][4];   // 2-deep weight prefetch (named buffers: static indexing)

  auto loadA = [&](int kb) {
    #pragma unroll
    for (int p = 0; p < 4; ++p)
      aR[p] = *(const float4*)(Xe + (size_t)(a_m + 32 * p) * D_ + kb + 4 * a_k4);
  };
  auto loadB = [&](int kb, float (&bR)[4][4]) {
    #pragma unroll
    for (int p = 0; p < 4; ++p) {
      const float* src = W1e + (size_t)(kb + 4 * b_kg + 8 * p) * N1_ + b_n;
      bR[p][0] = src[0];
      bR[p][1] = src[N1_];
      bR[p][2] = src[2 * N1_];
      bR[p][3] = src[3 * N1_];
    }
  };
  auto storeA = [&]() {
    #pragma unroll
    for (int p = 0; p < 4; ++p) {
      int m = a_m + 32 * p;
      *(uint2*)&Asm[m * SA + 4 * a_k4] =
          make_uint2(pack_bf16(aR[p].x, aR[p].y), pack_bf16(aR[p].z, aR[p].w));
    }
  };
  auto storeB = [&](float (&bR)[4][4]) {
    #pragma unroll
    for (int p = 0; p < 4; ++p) {
      int r = 4 * b_kg + 8 * p;
      *(uint2*)&Bsm[b_n * SA + r] =
          make_uint2(pack_bf16(bR[p][0], bR[p][1]), pack_bf16(bR[p][2], bR[p][3]));
    }
  };
  auto compute = [&]() {
    bf16x8 af[4], bf[4];
    #pragma unroll
    for (int i = 0; i < 4; ++i) {
      af[i] = *(const bf16x8*)&Asm[(wm + i * 16 + (lane & 15)) * SA + ((lane >> 4) << 3)];
      bf[i] = *(const bf16x8*)&Bsm[(wn + i * 16 + (lane & 15)) * SA + ((lane >> 4) << 3)];
    }
    __builtin_amdgcn_s_setprio(1);
    #pragma unroll
    for (int i = 0; i < 4; ++i)
      #pragma unroll
      for (int j = 0; j < 4; ++j)
        acc[i][j] = __builtin_amdgcn_mfma_f32_16x16x32_bf16(af[i], bf[j], acc[i][j], 0, 0, 0);
    __builtin_amdgcn_s_setprio(0);
  };

  loadA(0);             // A tile 0 (1-deep: X is L2-resident after first nt-block)
  loadB(0,  bRa);       // weight tile 0
  loadB(32, bRb);       // weight tile 1 — weights 2 K-tiles in flight, never drained
  #pragma unroll 1
  for (int kt = 0; kt < D_ / 32 - 2; kt += 2) {
    // ---- even step: consume tile kt (bRa) ----
    BARRIER_PRE();
    storeA(); storeB(bRa);                 // compiler emits counted vmcnt here (not 0)
    loadB((kt + 2) * 32, bRa);             // refill 2 ahead
    loadA((kt + 1) * 32);
    BARRIER_POST();
    compute();

    // ---- odd step: consume tile kt+1 (bRb) ----
    BARRIER_PRE();
    storeA(); storeB(bRb);
    loadB((kt + 3) * 32, bRb);
    loadA((kt + 2) * 32);
    BARRIER_POST();
    compute();
  }
  // ---- peeled tail: tiles NT-2 (bRa) and NT-1 (bRb), no weight prefetch ----
  BARRIER_PRE();
  storeA(); storeB(bRa);
  loadA((D_ / 32 - 1) * 32);
  BARRIER_POST();
  compute();
  BARRIER_PRE();
  storeA(); storeB(bRb);
  BARRIER_POST();
  compute();

  // epilogue: bias -> swiglu(pair via shfl_xor 1) -> Act bf16
  uint16_t* Acte = Act + (size_t)e * T_ * H_;
  #pragma unroll
  for (int j = 0; j < 4; ++j) {
    int col = nt * 128 + wn + j * 16 + (lane & 15);
    float bias = B1[e * N1_ + col];
    #pragma unroll
    for (int i = 0; i < 4; ++i) {
      #pragma unroll
      for (int r = 0; r < 4; ++r) {
        float h = acc[i][j][r] + bias;            // each lane adds ITS column's bias
        float partner = __shfl_xor(h, 1, 64);     // odd lane's (lin) value -> even lane
        if ((lane & 1) == 0) {
          float xg = fminf(h, 7.0f);
          float xl = fminf(fmaxf(partner, -7.0f), 7.0f);
          float sw = xg / (1.0f + __expf(-1.702f * xg));
          int m = wm + i * 16 + ((lane >> 4) << 2) + r;
          Acte[m * H_ + (col >> 1)] = f2bf(sw * (xl + 1.0f));
        }
      }
    }
  }
}

// ---------------- Kernel 2: OUT = Act @ W2 + b2 (fp32 out) ----------------
__global__ __launch_bounds__(256) void k2_gemm(
    const uint16_t* __restrict__ Act, const float* __restrict__ W2,
    const float* __restrict__ B2, float* __restrict__ OUT) {
  int blk = blockIdx.x;                 // 512 blocks
  int e  = (blk & 7) + ((blk >> 6) << 3);
  int nt = (blk >> 3) & 7;              // 8 column tiles of 128 over D=1024

  __shared__ uint16_t Asm[128 * SA];
  __shared__ uint16_t Bsm[128 * SA];

  int tid  = threadIdx.x;
  int lane = tid & 63;
  int w    = tid >> 6;
  int wm   = (w & 1) << 6;
  int wn   = (w >> 1) << 6;

  f32x4 acc[4][4];
  #pragma unroll
  for (int i = 0; i < 4; ++i)
    #pragma unroll
    for (int j = 0; j < 4; ++j) { f32x4 z = {0.f,0.f,0.f,0.f}; acc[i][j] = z; }

  const uint16_t* Ae  = Act + (size_t)e * T_ * H_;
  const float*    W2e = W2  + (size_t)e * H_ * D_ + nt * 128;

  int a_k2 = tid & 3;    // A: ushort8 (16B) at k0=8*a_k2, rows a_m+64p
  int a_m  = tid >> 2;
  int b_n  = tid & 127;
  int b_kg = tid >> 7;

  uint4 aR[2];
  float bRa[4][4], bRb[4][4];   // 2-deep weight prefetch

  auto loadA = [&](int kb) {
    #pragma unroll
    for (int p = 0; p < 2; ++p)
      aR[p] = *(const uint4*)(Ae + (size_t)(a_m + 64 * p) * H_ + kb + 8 * a_k2);
  };
  auto loadB = [&](int kb, float (&bR)[4][4]) {
    #pragma unroll
    for (int p = 0; p < 4; ++p) {
      const float* src = W2e + (size_t)(kb + 4 * b_kg + 8 * p) * D_ + b_n;
      bR[p][0] = src[0];
      bR[p][1] = src[D_];
      bR[p][2] = src[2 * D_];
      bR[p][3] = src[3 * D_];
    }
  };
  auto storeA = [&]() {
    #pragma unroll
    for (int p = 0; p < 2; ++p)
      *(uint4*)&Asm[(a_m + 64 * p) * SA + 8 * a_k2] = aR[p];
  };
  auto storeB = [&](float (&bR)[4][4]) {
    #pragma unroll
    for (int p = 0; p < 4; ++p) {
      int r = 4 * b_kg + 8 * p;
      *(uint2*)&Bsm[b_n * SA + r] =
          make_uint2(pack_bf16(bR[p][0], bR[p][1]), pack_bf16(bR[p][2], bR[p][3]));
    }
  };
  auto compute = [&]() {
    bf16x8 af[4], bf[4];
    #pragma unroll
    for (int i = 0; i < 4; ++i) {
      af[i] = *(const bf16x8*)&Asm[(wm + i * 16 + (lane & 15)) * SA + ((lane >> 4) << 3)];
      bf[i] = *(const bf16x8*)&Bsm[(wn + i * 16 + (lane & 15)) * SA + ((lane >> 4) << 3)];
    }
    __builtin_amdgcn_s_setprio(1);
    #pragma unroll
    for (int i = 0; i < 4; ++i)
      #pragma unroll
      for (int j = 0; j < 4; ++j)
        acc[i][j] = __builtin_amdgcn_mfma_f32_16x16x32_bf16(af[i], bf[j], acc[i][j], 0, 0, 0);
    __builtin_amdgcn_s_setprio(0);
  };

  loadA(0);
  loadB(0,  bRa);
  loadB(32, bRb);
  #pragma unroll 1
  for (int kt = 0; kt < H_ / 32 - 2; kt += 2) {
    // ---- even step ----
    BARRIER_PRE();
    storeA(); storeB(bRa);
    loadB((kt + 2) * 32, bRa);
    loadA((kt + 1) * 32);
    BARRIER_POST();
    compute();

    // ---- odd step ----
    BARRIER_PRE();
    storeA(); storeB(bRb);
    loadB((kt + 3) * 32, bRb);
    loadA((kt + 2) * 32);
    BARRIER_POST();
    compute();
  }
  // ---- peeled tail ----
  BARRIER_PRE();
  storeA(); storeB(bRa);
  loadA((H_ / 32 - 1) * 32);
  BARRIER_POST();
  compute();
  BARRIER_PRE();
  storeA(); storeB(bRb);
  BARRIER_POST();
  compute();

  float* Oe = OUT + (size_t)e * T_ * D_;
  #pragma unroll
  for (int j = 0; j < 4; ++j) {
    int col = nt * 128 + wn + j * 16 + (lane & 15);
    float bias = B2[e * D_ + col];
    #pragma unroll
    for (int i = 0; i < 4; ++i) {
      #pragma unroll
      for (int r = 0; r < 4; ++r) {
        int m = wm + i * 16 + ((lane >> 4) << 2) + r;
        Oe[(size_t)m * D_ + col] = acc[i][j][r] + bias;
      }
    }
  }
}

extern "C" void kernel_launch(void* const* d_in, const int* in_sizes, int n_in,
                              void* d_out, int out_size, void* d_ws, size_t ws_size,
                              hipStream_t stream) {
  const float* X  = (const float*)d_in[0];
  const float* W1 = (const float*)d_in[1];
  const float* B1 = (const float*)d_in[2];
  const float* W2 = (const float*)d_in[3];
  const float* B2 = (const float*)d_in[4];
  float* OUT = (float*)d_out;
  uint16_t* Act = (uint16_t*)d_ws;  // 64*128*1024 bf16 = 16 MB

  k1_gemm_swiglu<<<dim3(E_ * 16), dim3(256), 0, stream>>>(X, W1, B1, Act);
  k2_gemm<<<dim3(E_ * 8), dim3(256), 0, stream>>>(Act, W2, B2, OUT);
}